// Round 4
// baseline (2920.829 us; speedup 1.0000x reference)
//
#include <hip/hip_runtime.h>

static constexpr int   BATCH = 131072;
static constexpr int   TS    = 30;
static constexpr int   DD    = 10;
static constexpr int   HH    = 20;
static constexpr float EPSV  = 1e-5f;
static constexpr float INV_B = 1.0f / (float)BATCH;

static constexpr int NBLK = 256;   // 1 block/CU
static constexpr int NTHR = 512;   // 8 waves/CU = 2 waves/SIMD; RPT = 1
static constexpr int NS   = 8;     // atomic spread slots per reduced value
static constexpr int NVA  = 230;   // phase-A values: 210 tri second-moments + 20 sums
static constexpr int NVB  = 40;    // phase-B values: 20 sums + 20 sumsq of y2
static constexpr int STRA = NVA * NS;  // floats per t in redA
static constexpr int STRB = NVB * NS;  // floats per t in redB
static constexpr int NBAR = TS * 2;    // 60 grid barriers

__device__ __forceinline__ int tri(int k, int l) {  // k <= l, upper-tri linear index
    return k * (41 - k) / 2 + (l - k);
}

template <int CTRL>
__device__ __forceinline__ float dpp_add(float v) {
    int x = __builtin_amdgcn_update_dpp(0, __float_as_int(v), CTRL, 0xF, 0xF, true);
    return v + __int_as_float(x);
}

// Sum within each 16-lane row; lane 15 of each 16 holds the row total.
__device__ __forceinline__ float rowsum16(float v) {
    v = dpp_add<0x111>(v);
    v = dpp_add<0x112>(v);
    v = dpp_add<0x114>(v);
    v = dpp_add<0x118>(v);
    return v;
}

__device__ __forceinline__ float aload(float* p) {
    return __hip_atomic_load(p, __ATOMIC_RELAXED, __HIP_MEMORY_SCOPE_AGENT);
}

// Hand-rolled grid barrier on a phase-unique counter (64B padded).
__device__ __forceinline__ void gbar(unsigned* __restrict__ c, int tid) {
    __syncthreads();   // drains this block's vmem (incl. atomics) before arrival
    if (tid == 0) {
        __hip_atomic_fetch_add(c, 1u, __ATOMIC_RELEASE, __HIP_MEMORY_SCOPE_AGENT);
        while (__hip_atomic_load(c, __ATOMIC_ACQUIRE, __HIP_MEMORY_SCOPE_AGENT) < (unsigned)NBLK)
            __builtin_amdgcn_s_sleep(1);
    }
    __syncthreads();
}

__global__ void __launch_bounds__(NTHR, 1)
rnn_bn_kernel(const float* __restrict__ x,
              const float* __restrict__ g0, const float* __restrict__ be0,
              const float* __restrict__ W1, const float* __restrict__ b1,
              const float* __restrict__ g1, const float* __restrict__ be1,
              const float* __restrict__ W2, const float* __restrict__ b2,
              const float* __restrict__ g2, const float* __restrict__ be2,
              const float* __restrict__ W3, const float* __restrict__ b3,
              float* __restrict__ out,
              float* __restrict__ redA, float* __restrict__ redB,
              unsigned* __restrict__ ctr)
{
    __shared__ float lred[32 * NVA];         // 32 sixteen-lane groups x 230
    __shared__ float sM[210], sS[20];
    __shared__ float sCov[400];
    __shared__ float sW1[400], sW2[400], sW3[200], sB3[10];
    __shared__ float sA0[20], sC0[20], sMu[20];
    __shared__ float sA1[20], sC1[20];
    __shared__ float sA2[20], sC2[20];

    const int tid    = threadIdx.x;
    const int grp    = tid >> 4;
    const bool lane15 = (tid & 15) == 15;
    const int slot   = blockIdx.x & (NS - 1);
    const int gt     = blockIdx.x * NTHR + tid;   // one batch row per thread

    float prev[DD];
#pragma unroll
    for (int d = 0; d < DD; ++d) prev[d] = 0.0f;

    // preload x_0
    float xt[DD];
    {
        const float* px = x + (size_t)gt * TS * DD;
#pragma unroll
        for (int d = 0; d < DD; ++d) xt[d] = px[d];
    }

    for (int t = 0; t < TS; ++t) {
        // ================= phase A: second moments of h0 = [x_t, prev] ==========
        float h0[2 * DD];
#pragma unroll
        for (int d = 0; d < DD; ++d) { h0[d] = xt[d]; h0[DD + d] = prev[d]; }

        {
            int v = 0;
#pragma unroll
            for (int k = 0; k < 2 * DD; ++k) {
#pragma unroll
                for (int l = k; l < 2 * DD; ++l) {
                    float r = rowsum16(h0[k] * h0[l]);
                    if (lane15) lred[grp * NVA + v] = r;
                    ++v;
                }
            }
#pragma unroll
            for (int k = 0; k < 2 * DD; ++k) {
                float r = rowsum16(h0[k]);
                if (lane15) lred[grp * NVA + 210 + k] = r;
            }
        }
        __syncthreads();
        if (tid < NVA) {
            float acc = 0.0f;
#pragma unroll
            for (int g = 0; g < 32; ++g) acc += lred[g * NVA + tid];
            atomicAdd(redA + (size_t)t * STRA + tid * NS + slot, acc);
        }
        gbar(ctr + (size_t)(t * 2 + 0) * 16, tid);

        // ---- readback M, S; stage weights (all index ranges within 0..511!)
        if (tid < NVA) {
            float* p = redA + (size_t)t * STRA + tid * NS;
            float s = 0.0f;
#pragma unroll
            for (int i = 0; i < NS; ++i) s += aload(p + i);
            if (tid < 210) sM[tid] = s; else sS[tid - 210] = s;
        }
        if (tid < 400) { sW1[tid] = W1[t * 400 + tid]; sW2[tid] = W2[t * 400 + tid]; }
        if (tid < 200) sW3[tid] = W3[t * 200 + tid];
        if (tid >= 500 && tid < 510) sB3[tid - 500] = b3[t * DD + (tid - 500)];
        __syncthreads();

        // ---- BN0 params
        if (tid < 20) {
            float mu  = sS[tid] * INV_B;
            float var = fmaf(-mu, mu, sM[tri(tid, tid)] * INV_B);
            float a   = g0[t * 20 + tid] * rsqrtf(var + EPSV);
            sA0[tid] = a;
            sC0[tid] = fmaf(-mu, a, be0[t * 20 + tid]);
            sMu[tid] = mu;
        }
        __syncthreads();

        // ---- covariance matrix (full 20x20)
        if (tid < 400) {
            int k = tid / 20, l = tid % 20;
            int a = k < l ? k : l, b = k < l ? l : k;
            sCov[tid] = fmaf(-sMu[k], sMu[l], sM[tri(a, b)] * INV_B);
        }
        __syncthreads();

        // ---- analytic BN1 params: y1 = W1 * (A0*h0 + C0)   (b1 cancels in BN)
        if (tid < 20) {
            const int j = tid;
            float u[20];
            float cj = 0.0f;
#pragma unroll
            for (int k = 0; k < 20; ++k) {
                float w = sW1[j * 20 + k];
                u[k] = w * sA0[k];
                cj   = fmaf(w, sC0[k], cj);
            }
            float m1 = cj;
#pragma unroll
            for (int k = 0; k < 20; ++k) m1 = fmaf(u[k], sMu[k], m1);
            float var1 = 0.0f;
#pragma unroll
            for (int k = 0; k < 20; ++k) {
                float w = 0.0f;
#pragma unroll
                for (int l = 0; l < 20; ++l) w = fmaf(sCov[k * 20 + l], u[l], w);
                var1 = fmaf(u[k], w, var1);
            }
            float a1 = g1[t * 20 + j] * rsqrtf(var1 + EPSV);
            sA1[j] = a1;
            sC1[j] = fmaf(-m1, a1, be1[t * 20 + j]);
        }
        __syncthreads();

        // ================= forward through layer 1 and 2 =========================
        float hn[20];
#pragma unroll
        for (int k = 0; k < 20; ++k) hn[k] = fmaf(h0[k], sA0[k], sC0[k]);

        float h1[20];
#pragma unroll
        for (int j = 0; j < 20; ++j) {
            float y = 0.0f;
#pragma unroll
            for (int k = 0; k < 20; ++k) y = fmaf(sW1[j * 20 + k], hn[k], y);
            h1[j] = fmaxf(fmaf(y, sA1[j], sC1[j]), 0.0f);
        }

        float y2[20];
#pragma unroll
        for (int j = 0; j < 20; ++j) {
            float y = 0.0f;
#pragma unroll
            for (int k = 0; k < 20; ++k) y = fmaf(sW2[j * 20 + k], h1[k], y);
            y2[j] = y;   // b2 cancels in BN2
        }

        // ================= phase B: stats of y2 ==================================
        __syncthreads();   // lred reuse safe
        {
#pragma unroll
            for (int j = 0; j < 20; ++j) {
                float r = rowsum16(y2[j]);
                if (lane15) lred[grp * NVA + j] = r;
            }
#pragma unroll
            for (int j = 0; j < 20; ++j) {
                float r = rowsum16(y2[j] * y2[j]);
                if (lane15) lred[grp * NVA + 20 + j] = r;
            }
        }
        __syncthreads();
        if (tid < NVB) {
            float acc = 0.0f;
#pragma unroll
            for (int g = 0; g < 32; ++g) acc += lred[g * NVA + tid];
            atomicAdd(redB + (size_t)t * STRB + tid * NS + slot, acc);
        }

        // prefetch x_{t+1}; latency hides under barrier spin
        float xn[DD];
        if (t + 1 < TS) {
            const float* px = x + ((size_t)gt * TS + (t + 1)) * DD;
#pragma unroll
            for (int d = 0; d < DD; ++d) xn[d] = px[d];
        }
        gbar(ctr + (size_t)(t * 2 + 1) * 16, tid);

        // ---- BN2 params
        if (tid < 20) {
            float* p = redB + (size_t)t * STRB + tid * NS;
            float* q = redB + (size_t)t * STRB + (tid + 20) * NS;
            float s = 0.0f, ss = 0.0f;
#pragma unroll
            for (int i = 0; i < NS; ++i) { s += aload(p + i); ss += aload(q + i); }
            float m   = s * INV_B;
            float var = fmaf(-m, m, ss * INV_B);
            float a   = g2[t * 20 + tid] * rsqrtf(var + EPSV);
            sA2[tid] = a;
            sC2[tid] = fmaf(-m, a, be2[t * 20 + tid]);
        }
        __syncthreads();

        // ================= layer 3 + output ======================================
        float h2[20];
#pragma unroll
        for (int j = 0; j < 20; ++j)
            h2[j] = fmaxf(fmaf(y2[j], sA2[j], sC2[j]), 0.0f);

        {
            float* po = out + ((size_t)gt * TS + t) * DD;
#pragma unroll
            for (int d = 0; d < DD; ++d) {
                float a = sB3[d];
#pragma unroll
                for (int j = 0; j < 20; ++j)
                    a = fmaf(sW3[d * 20 + j], h2[j], a);
                po[d] = a;
                prev[d] = a;
            }
        }
        if (t + 1 < TS) {
#pragma unroll
            for (int d = 0; d < DD; ++d) xt[d] = xn[d];
        }
        __syncthreads();   // protect LDS (sA*/sW*) before next step overwrites
    }
}

extern "C" void kernel_launch(void* const* d_in, const int* in_sizes, int n_in,
                              void* d_out, int out_size, void* d_ws, size_t ws_size,
                              hipStream_t stream) {
    const float* x   = (const float*)d_in[0];
    const float* g0  = (const float*)d_in[1];
    const float* be0 = (const float*)d_in[2];
    const float* W1  = (const float*)d_in[3];
    const float* b1  = (const float*)d_in[4];
    const float* g1  = (const float*)d_in[5];
    const float* be1 = (const float*)d_in[6];
    const float* W2  = (const float*)d_in[7];
    const float* b2  = (const float*)d_in[8];
    const float* g2  = (const float*)d_in[9];
    const float* be2 = (const float*)d_in[10];
    const float* W3  = (const float*)d_in[11];
    const float* b3  = (const float*)d_in[12];
    float* out = (float*)d_out;

    const size_t redA_f = (size_t)TS * STRA;            // 55200 floats
    const size_t redB_f = (size_t)TS * STRB;            //  9600 floats
    float*    redA = (float*)d_ws;
    float*    redB = redA + redA_f;
    unsigned* ctr  = (unsigned*)(redB + redB_f);        // [NBAR][16]

    const size_t total_bytes = (redA_f + redB_f) * 4 + (size_t)NBAR * 16 * 4;
    hipMemsetAsync(d_ws, 0, total_bytes, stream);

    void* args[] = { &x, &g0, &be0, &W1, &b1, &g1, &be1, &W2, &b2, &g2, &be2,
                     &W3, &b3, &out, &redA, &redB, &ctr };
    hipLaunchCooperativeKernel((const void*)rnn_bn_kernel, dim3(NBLK), dim3(NTHR),
                               args, 0, stream);
}

// Round 5
// 2107.530 us; speedup vs baseline: 1.3859x; 1.3859x over previous
//
#include <hip/hip_runtime.h>

static constexpr int   BATCH = 131072;
static constexpr int   TS    = 30;
static constexpr int   DD    = 10;
static constexpr int   HH    = 20;
static constexpr float EPSV  = 1e-5f;
static constexpr float INV_B = 1.0f / (float)BATCH;

static constexpr int NBLK = 256;   // 1 block/CU, cooperative
static constexpr int NTHR = 512;   // 8 waves/CU
static constexpr int NS   = 8;     // stat accumulation slots (blockIdx&7)
static constexpr int GRPS = 8;     // barrier tree groups
static constexpr int GSZ  = NBLK / GRPS;   // 32 arrivals per group counter
static constexpr int NVA  = 230;   // phase-A: 210 tri second-moments + 20 sums
static constexpr int NVB  = 40;    // phase-B: 20 sums + 20 sumsq
static constexpr int STRA = NVA * NS;
static constexpr int STRB = NVB * NS;
static constexpr int NPH  = TS * 2;        // 60 barrier phases
static constexpr int CTRW = 160;           // uints per phase in ctr (64B-padded counters)

__device__ __forceinline__ int tri(int k, int l) {  // k <= l
    return k * (41 - k) / 2 + (l - k);
}

template <int CTRL>
__device__ __forceinline__ float dpp_add(float v) {
    int x = __builtin_amdgcn_update_dpp(0, __float_as_int(v), CTRL, 0xF, 0xF, true);
    return v + __int_as_float(x);
}

__device__ __forceinline__ float rowsum16(float v) {
    v = dpp_add<0x111>(v);
    v = dpp_add<0x112>(v);
    v = dpp_add<0x114>(v);
    v = dpp_add<0x118>(v);
    return v;   // lane 15 of each 16 holds the total
}

// Relaxed tree barrier: no release (stats are device-scope atomics, visible at
// coherence point once vmcnt drains at the entry __syncthreads), no acquire
// spinning. ONE acquire fence on exit so post-barrier CACHED loads see fresh data.
__device__ __forceinline__ void gbar(unsigned* __restrict__ base, int tid, int grp8) {
    __syncthreads();   // drains this block's vmem (incl. atomicAdds) before arrival
    if (tid == 0) {
        unsigned old = __hip_atomic_fetch_add(base + grp8 * 16, 1u,
                                              __ATOMIC_RELAXED, __HIP_MEMORY_SCOPE_AGENT);
        if (old == (unsigned)(GSZ - 1))
            __hip_atomic_fetch_add(base + 128, 1u,
                                   __ATOMIC_RELAXED, __HIP_MEMORY_SCOPE_AGENT);
        while (__hip_atomic_load(base + 128, __ATOMIC_RELAXED,
                                 __HIP_MEMORY_SCOPE_AGENT) < (unsigned)GRPS)
            __builtin_amdgcn_s_sleep(2);
        __builtin_amdgcn_fence(__ATOMIC_ACQUIRE, "agent");  // single L1/L2 inv
    }
    __syncthreads();
}

__global__ void __launch_bounds__(NTHR, 1)
rnn_bn_kernel(const float* __restrict__ x,
              const float* __restrict__ g0, const float* __restrict__ be0,
              const float* __restrict__ W1, const float* __restrict__ b1,
              const float* __restrict__ g1, const float* __restrict__ be1,
              const float* __restrict__ W2, const float* __restrict__ b2,
              const float* __restrict__ g2, const float* __restrict__ be2,
              const float* __restrict__ W3, const float* __restrict__ b3,
              float* __restrict__ out,
              float* __restrict__ redA, float* __restrict__ redB,
              unsigned* __restrict__ ctr)
{
    __shared__ float lred[32 * NVA];
    __shared__ float sM[230];                 // 210 tri moments + 20 sums
    __shared__ float sMu[20], sCov[400], sU[400], sP[400];
    __shared__ float sW1[400], sW2[400], sW3[200], sB3[10];
    __shared__ float sG0[20], sBe0[20], sG1[20], sBe1[20], sG2[20], sBe2[20];
    __shared__ float sA0[20], sC0[20], sA1[20], sC1[20], sA2[20], sC2[20];

    const int tid     = threadIdx.x;
    const int grp     = tid >> 4;             // 0..31
    const bool lane15 = (tid & 15) == 15;
    const int slot    = blockIdx.x & (NS - 1);
    const int grp8    = blockIdx.x & (GRPS - 1);
    const int gt      = blockIdx.x * NTHR + tid;   // one batch row per thread

    float prev[DD];
#pragma unroll
    for (int d = 0; d < DD; ++d) prev[d] = 0.0f;

    float xt[DD];
    {
        const float* px = x + (size_t)gt * TS * DD;
#pragma unroll
        for (int d = 0; d < DD; ++d) xt[d] = px[d];
    }

    for (int t = 0; t < TS; ++t) {
        // ---- stage weights & affine params for this step (off critical path;
        //      LDS survives the barrier's cache inv)
        if (tid < 400) { sW1[tid] = W1[t * 400 + tid]; sW2[tid] = W2[t * 400 + tid]; }
        if (tid < 200) sW3[tid] = W3[t * 200 + tid];
        if (tid >= 400 && tid < 420) { sG0[tid-400] = g0[t*20 + tid-400]; sBe0[tid-400] = be0[t*20 + tid-400]; }
        if (tid >= 420 && tid < 440) { sG1[tid-420] = g1[t*20 + tid-420]; sBe1[tid-420] = be1[t*20 + tid-420]; }
        if (tid >= 440 && tid < 460) { sG2[tid-440] = g2[t*20 + tid-440]; sBe2[tid-440] = be2[t*20 + tid-440]; }
        if (tid >= 460 && tid < 470) sB3[tid-460] = b3[t*DD + tid-460];

        // ================= phase A: second moments of h0 = [x_t, prev] =========
#define H0E(i) ((i) < DD ? xt[i] : prev[(i) - DD])
        {
            int v = 0;
#pragma unroll
            for (int k = 0; k < 2 * DD; ++k) {
#pragma unroll
                for (int l = k; l < 2 * DD; ++l) {
                    float r = rowsum16(H0E(k) * H0E(l));
                    if (lane15) lred[grp * NVA + v] = r;
                    ++v;
                }
            }
#pragma unroll
            for (int k = 0; k < 2 * DD; ++k) {
                float r = rowsum16(H0E(k));
                if (lane15) lred[grp * NVA + 210 + k] = r;
            }
        }
        __syncthreads();
        if (tid < NVA) {
            float acc = 0.0f;
#pragma unroll
            for (int g = 0; g < 32; ++g) acc += lred[g * NVA + tid];
            atomicAdd(redA + (size_t)t * STRA + tid * NS + slot, acc);
        }
        gbar(ctr + (size_t)(t * 2 + 0) * CTRW, tid, grp8);

        // ---- readback (normal cached loads; fresh after the acquire inv)
        if (tid < NVA) {
            const float* p = redA + (size_t)t * STRA + tid * NS;
            float s = 0.0f;
#pragma unroll
            for (int i = 0; i < NS; ++i) s += p[i];
            sM[tid] = s;
        }
        __syncthreads();

        // ---- BN0 params
        if (tid < 20) {
            float mu  = sM[210 + tid] * INV_B;
            float var = fmaf(-mu, mu, sM[tri(tid, tid)] * INV_B);
            float a   = sG0[tid] * rsqrtf(var + EPSV);
            sA0[tid] = a;
            sC0[tid] = fmaf(-mu, a, sBe0[tid]);
            sMu[tid] = mu;
        }
        __syncthreads();

        // ---- covariance + U = W1 ∘ A0 (parallel over 400)
        if (tid < 400) {
            int k = tid / 20, l = tid % 20;
            int a = k < l ? k : l, b = k < l ? l : k;
            sCov[tid] = fmaf(-sMu[k], sMu[l], sM[tri(a, b)] * INV_B);
            sU[tid]   = sW1[tid] * sA0[l];
        }
        __syncthreads();

        // ---- P[j,k] = U[j,k] * (Cov[k,:] · U[j,:])
        if (tid < 400) {
            int j = tid / 20, k = tid % 20;
            float acc = 0.0f;
#pragma unroll
            for (int l = 0; l < 20; ++l)
                acc = fmaf(sCov[k * 20 + l], sU[j * 20 + l], acc);
            sP[tid] = acc * sU[tid];
        }
        __syncthreads();

        // ---- analytic BN1 params (b1 cancels in BN)
        if (tid < 20) {
            const int j = tid;
            float var1 = 0.0f, m1 = 0.0f;
#pragma unroll
            for (int k = 0; k < 20; ++k) {
                var1 += sP[j * 20 + k];
                m1    = fmaf(sU[j * 20 + k], sMu[k], m1);
                m1    = fmaf(sW1[j * 20 + k], sC0[k], m1);
            }
            float a1 = sG1[j] * rsqrtf(var1 + EPSV);
            sA1[j] = a1;
            sC1[j] = fmaf(-m1, a1, sBe1[j]);
        }
        __syncthreads();

        // ================= forward layers 1,2 ===================================
        float hn[20];
#pragma unroll
        for (int k = 0; k < 20; ++k) hn[k] = fmaf(H0E(k), sA0[k], sC0[k]);
#undef H0E

        float h1[20];
#pragma unroll
        for (int j = 0; j < 20; ++j) {
            float y = 0.0f;
#pragma unroll
            for (int k = 0; k < 20; ++k) y = fmaf(sW1[j * 20 + k], hn[k], y);
            h1[j] = fmaxf(fmaf(y, sA1[j], sC1[j]), 0.0f);
        }

        float y2[20];
#pragma unroll
        for (int j = 0; j < 20; ++j) {
            float y = 0.0f;
#pragma unroll
            for (int k = 0; k < 20; ++k) y = fmaf(sW2[j * 20 + k], h1[k], y);
            y2[j] = y;   // b2 cancels in BN2
        }

        // ================= phase B: stats of y2 =================================
        {
#pragma unroll
            for (int j = 0; j < 20; ++j) {
                float r = rowsum16(y2[j]);
                if (lane15) lred[grp * NVA + j] = r;
            }
#pragma unroll
            for (int j = 0; j < 20; ++j) {
                float r = rowsum16(y2[j] * y2[j]);
                if (lane15) lred[grp * NVA + 20 + j] = r;
            }
        }
        __syncthreads();
        if (tid < NVB) {
            float acc = 0.0f;
#pragma unroll
            for (int g = 0; g < 32; ++g) acc += lred[g * NVA + tid];
            atomicAdd(redB + (size_t)t * STRB + tid * NS + slot, acc);
        }

        // prefetch x_{t+1} into registers (survives the inv; x is read-only)
        float xn[DD];
        if (t + 1 < TS) {
            const float* px = x + ((size_t)gt * TS + (t + 1)) * DD;
#pragma unroll
            for (int d = 0; d < DD; ++d) xn[d] = px[d];
        }
        gbar(ctr + (size_t)(t * 2 + 1) * CTRW, tid, grp8);

        // ---- BN2 params (cached readback)
        if (tid < 20) {
            const float* p = redB + (size_t)t * STRB + tid * NS;
            const float* q = redB + (size_t)t * STRB + (tid + 20) * NS;
            float s = 0.0f, ss = 0.0f;
#pragma unroll
            for (int i = 0; i < NS; ++i) { s += p[i]; ss += q[i]; }
            float m   = s * INV_B;
            float var = fmaf(-m, m, ss * INV_B);
            float a   = sG2[tid] * rsqrtf(var + EPSV);
            sA2[tid] = a;
            sC2[tid] = fmaf(-m, a, sBe2[tid]);
        }
        __syncthreads();

        // ================= layer 3 + output =====================================
        float h2[20];
#pragma unroll
        for (int j = 0; j < 20; ++j)
            h2[j] = fmaxf(fmaf(y2[j], sA2[j], sC2[j]), 0.0f);

        {
            float* po = out + ((size_t)gt * TS + t) * DD;
#pragma unroll
            for (int d = 0; d < DD; ++d) {
                float a = sB3[d];
#pragma unroll
                for (int j = 0; j < 20; ++j)
                    a = fmaf(sW3[d * 20 + j], h2[j], a);
                po[d] = a;
                prev[d] = a;
            }
        }
        if (t + 1 < TS) {
#pragma unroll
            for (int d = 0; d < DD; ++d) xt[d] = xn[d];
        }
        __syncthreads();   // protect LDS before next step's weight staging
    }
}

extern "C" void kernel_launch(void* const* d_in, const int* in_sizes, int n_in,
                              void* d_out, int out_size, void* d_ws, size_t ws_size,
                              hipStream_t stream) {
    const float* x   = (const float*)d_in[0];
    const float* g0  = (const float*)d_in[1];
    const float* be0 = (const float*)d_in[2];
    const float* W1  = (const float*)d_in[3];
    const float* b1  = (const float*)d_in[4];
    const float* g1  = (const float*)d_in[5];
    const float* be1 = (const float*)d_in[6];
    const float* W2  = (const float*)d_in[7];
    const float* b2  = (const float*)d_in[8];
    const float* g2  = (const float*)d_in[9];
    const float* be2 = (const float*)d_in[10];
    const float* W3  = (const float*)d_in[11];
    const float* b3  = (const float*)d_in[12];
    float* out = (float*)d_out;

    const size_t redA_f = (size_t)TS * STRA;        // 55200 floats
    const size_t redB_f = (size_t)TS * STRB;        //  9600 floats
    float*    redA = (float*)d_ws;
    float*    redB = redA + redA_f;
    unsigned* ctr  = (unsigned*)(redB + redB_f);    // [NPH][CTRW]

    const size_t total_bytes = (redA_f + redB_f) * 4 + (size_t)NPH * CTRW * 4;
    hipMemsetAsync(d_ws, 0, total_bytes, stream);

    void* args[] = { &x, &g0, &be0, &W1, &b1, &g1, &be1, &W2, &b2, &g2, &be2,
                     &W3, &b3, &out, &redA, &redB, &ctr };
    hipLaunchCooperativeKernel((const void*)rnn_bn_kernel, dim3(NBLK), dim3(NTHR),
                               args, 0, stream);
}